// Round 9
// baseline (829.150 us; speedup 1.0000x reference)
//
#include <hip/hip_runtime.h>
#include <hip/hip_bf16.h>
#include <stdint.h>

using bf16 = __hip_bfloat16;
using u64 = unsigned long long;

constexpr int B_ = 2;
constexpr int N_ = 2304;   // 48*48 post-conv nodes

// Workspace layout (float offsets). Max = 1,560,640 floats = 6.24 MB.
constexpr int OFF_WC2   = 0;        // conv w  [tap][ic][oc] (9*64*64)
constexpr int OFF_WT2   = 36864;    // tconv w [tap][ic][oc]
constexpr int OFF_W1F   = 73728;    // [64][64]
constexpr int OFF_W2F   = 77824;
constexpr int OFF_WOUTF = 81920;    // [128][64]
constexpr int OFF_A1F   = 90112;    // 128
constexpr int OFF_A2F   = 90240;
constexpr int OFF_AOUTF = 90368;
constexpr int OFF_CBF   = 90496;    // 64
constexpr int OFF_TBF   = 90560;    // 64
constexpr int OFF_FLAG  = 90624;    // 1: fp32 inputs; 0: bf16
constexpr int OFF_BAR   = 90632;    // grid-barrier counter (zeroed by memset)
constexpr int OFF_SQ    = 90688;    // [B*N]; SQ + six s-arrays contiguous
constexpr int OFF_S11   = 95296;
constexpr int OFF_S12   = 99904;
constexpr int OFF_S21   = 104512;
constexpr int OFF_S22   = 109120;
constexpr int OFF_S1O   = 113728;
constexpr int OFF_S2O   = 118336;
constexpr int OFF_KNN   = 122944;   // int [B*N][8] (7 used)
constexpr int OFF_BUF0  = 159808;   // 294912 floats each
constexpr int OFF_BUF1  = 454720;
constexpr int OFF_BUF2  = 749632;
constexpr int OFF_BUF3  = 1044544;
constexpr int OFF_PK    = 1339456;  // u64[4608][3][8] partials
// Lifetimes:
//  BUF0: featT (p0 -> p1 B-tiles, p2) -> h2 (p3 -> p4)
//  BUF1: Wh1_nc (p2 -> p3)            -> Whout_nc (p4 -> p5)
//  BUF2: feat_nc (p0 -> p1 A-rows)    -> h1 (p3 -> p4)
//  BUF3: Wh2_nc (p2 -> p3)            -> g  (p5 -> p6)

constexpr unsigned NBLK = 864;

__device__ __forceinline__ float bf2f_raw(unsigned short u) {
    return __uint_as_float(((unsigned int)u) << 16);
}

__device__ __forceinline__ unsigned int mono32(float f) {
    unsigned int u = __float_as_uint(f);
    return (u & 0x80000000u) ? ~u : (u | 0x80000000u);
}

__device__ __forceinline__ bool detect_f32(const void* conv_w) {
    const unsigned short* cw = (const unsigned short*)conv_w;
    float m = 0.f;
    #pragma unroll
    for (int u = 0; u < 64; ++u) {
        float v = fabsf(bf2f_raw(cw[u]));
        if (v < 3.0e38f) m = fmaxf(m, v);
    }
    return m > 1.0e4f;
}

// Grid-wide barrier: monotonic counter, device-scope atomics, release/acquire
// fences for cross-XCD visibility (Guideline 16).  Poll cap: a residency
// failure degrades to wrong-answer, not a hang.
__device__ __forceinline__ void gridbar(float* __restrict__ ws, unsigned target) {
    __syncthreads();
    if (threadIdx.x == 0) {
        __threadfence();                                     // release (wb L2)
        atomicAdd((unsigned*)(ws + OFF_BAR), 1u);
        int guard = 0;
        while (atomicAdd((unsigned*)(ws + OFF_BAR), 0u) < target) {
            __builtin_amdgcn_s_sleep(32);
            if (++guard > (1 << 20)) break;
        }
        __threadfence();                                     // acquire (inv)
    }
    __syncthreads();
}

// ---------------------------------------------------------------------------
// conv body reading RAW conv_w/conv_b (wave-uniform scalar-pipe addressing);
// produces values identical to the converted-weight path.
// ---------------------------------------------------------------------------
template <bool F32>
__device__ __forceinline__ void conv_body_raw(const void* __restrict__ x,
        const void* __restrict__ cw, const void* __restrict__ cb,
        float* __restrict__ ws, int n, int ocb, int b)
{
    int oy = n / 48, ox = n - (n / 48) * 48;
    size_t xb = (size_t)b * 64 * 9216;
    float acc[4] = {0, 0, 0, 0};

    for (int ky = 0; ky < 3; ++ky) {
        int iy = 2 * oy - 1 + ky;
        bool vy = (unsigned)iy < 96u;
        int iyc = vy ? iy : 0;
        for (int kx = 0; kx < 3; ++kx) {
            int ix = 2 * ox - 1 + kx;
            bool v = vy && ((unsigned)ix < 96u);
            int ixc = v ? ix : 0;
            size_t xoff = xb + iyc * 96 + ixc;
            int tap = ky * 3 + kx;
            #pragma unroll 8
            for (int ic = 0; ic < 64; ++ic) {
                float xv;
                if (F32) xv = ((const float*)x)[xoff + ic * 9216];
                else     xv = bf2f_raw(((const unsigned short*)x)[xoff + ic * 9216]);
                xv = v ? xv : 0.f;
                #pragma unroll
                for (int o = 0; o < 4; ++o) {
                    float wv;
                    size_t widx = ((size_t)(ocb + o) * 64 + ic) * 9 + tap;
                    if (F32) wv = ((const float*)cw)[widx];
                    else     wv = bf2f_raw(((const unsigned short*)cw)[widx]);
                    acc[o] += xv * wv;
                }
            }
        }
    }
    float* featT = ws + OFF_BUF0 + (size_t)b * 64 * N_;
    float ssum = 0.f;
    #pragma unroll
    for (int o = 0; o < 4; ++o) {
        float bv = F32 ? ((const float*)cb)[ocb + o]
                       : bf2f_raw(((const unsigned short*)cb)[ocb + o]);
        float f = acc[o] + bv;
        acc[o] = f;
        featT[(ocb + o) * N_ + n] = f;
        ssum += f * f;
    }
    *(float4*)(ws + OFF_BUF2 + ((size_t)(b * N_ + n) * 64 + ocb)) =
        make_float4(acc[0], acc[1], acc[2], acc[3]);
    atomicAdd(ws + OFF_SQ + b * N_ + n, ssum);
}

// ---------------------------------------------------------------------------
// attention body: softmax over 7-NN + ELU, one float4 channel group.
// ---------------------------------------------------------------------------
__device__ __forceinline__ void attn_body(
    const float* __restrict__ Wh_nc, const float* __restrict__ s1,
    const float* __restrict__ s2, const int* __restrict__ knn,
    float* __restrict__ out, int i, int b, int n, int c4)
{
    const int* kp = knn + (size_t)i * 8;
    int j[7];
    #pragma unroll
    for (int t = 0; t < 7; ++t) {
        int jt = kp[t];
        j[t] = ((unsigned)jt < (unsigned)N_) ? jt : 0;
    }
    float si = s1[i];
    const float* s2b = s2 + b * N_;
    float e[7];
    #pragma unroll
    for (int t = 0; t < 7; ++t) {
        float v = si + s2b[j[t]];
        e[t] = v > 0.f ? v : 0.2f * v;     // leaky_relu 0.2
    }
    float m = e[0];
    #pragma unroll
    for (int t = 1; t < 7; ++t) m = fmaxf(m, e[t]);
    float ssum = 0.f;
    #pragma unroll
    for (int t = 0; t < 7; ++t) { e[t] = __expf(e[t] - m); ssum += e[t]; }
    float inv = 1.f / ssum;
    #pragma unroll
    for (int t = 0; t < 7; ++t) e[t] *= inv;

    const float4* W4 = (const float4*)Wh_nc;
    float4 acc = make_float4(0.f, 0.f, 0.f, 0.f);
    #pragma unroll
    for (int t = 0; t < 7; ++t) {
        float4 v = W4[(size_t)(b * N_ + j[t]) * 16 + c4];
        acc.x += e[t] * v.x; acc.y += e[t] * v.y;
        acc.z += e[t] * v.z; acc.w += e[t] * v.w;
    }
    acc.x = acc.x > 0.f ? acc.x : expm1f(acc.x);
    acc.y = acc.y > 0.f ? acc.y : expm1f(acc.y);
    acc.z = acc.z > 0.f ? acc.z : expm1f(acc.z);
    acc.w = acc.w > 0.f ? acc.w : expm1f(acc.w);
    float* ob = out + (size_t)b * 64 * N_;
    ob[(c4 * 4 + 0) * N_ + n] = acc.x;
    ob[(c4 * 4 + 1) * N_ + n] = acc.y;
    ob[(c4 * 4 + 2) * N_ + n] = acc.z;
    ob[(c4 * 4 + 3) * N_ + n] = acc.w;
}

// ---------------------------------------------------------------------------
// K_ALL: the whole pipeline in ONE persistent kernel.  864 blocks x 256.
// The 8-launch version had a stable 170us residual independent of k2 time
// (~35-40us of which is real kernel work) -> launch/boundary overhead is the
// dominant cost.  Phases separated by software grid barriers.
// Residency proof: __launch_bounds__(256,4) -> VGPR<=128 -> 4 blocks/CU
// (1024 >= 864); LDS 32KB -> 5/CU.  All math verbatim from the 8-kernel
// version (k1 reads raw weights -> identical values).
// ---------------------------------------------------------------------------
__global__ __launch_bounds__(256, 4) void k_all(
    const void* __restrict__ x,
    const void* conv_w, const void* conv_b, const void* W1, const void* a1,
    const void* W2, const void* a2, const void* Wout, const void* aout,
    const void* tconv_w, const void* tconv_b,
    float* __restrict__ ws, void* __restrict__ outp)
{
    int bx = blockIdx.x, tid = threadIdx.x;

    // ---- P0: kc weight-prep (blocks 0..143) || k1 conv (blocks 144..431) ----
    if (bx < 144) {
        bool f32 = detect_f32(conv_w);
        int idx = bx * 256 + tid;   // < 36864
        if (idx == 0) ws[OFF_FLAG] = f32 ? 1.f : 0.f;
        {
            int tap = idx >> 12, ic = (idx >> 6) & 63, oc = idx & 63;
            if (f32) {
                ws[OFF_WC2 + idx] = ((const float*)conv_w)[(oc * 64 + ic) * 9 + tap];
                ws[OFF_WT2 + idx] = ((const float*)tconv_w)[(ic * 64 + oc) * 9 + tap];
            } else {
                ws[OFF_WC2 + idx] = bf2f_raw(((const unsigned short*)conv_w)[(oc * 64 + ic) * 9 + tap]);
                ws[OFF_WT2 + idx] = bf2f_raw(((const unsigned short*)tconv_w)[(ic * 64 + oc) * 9 + tap]);
            }
        }
        if (idx < 4096) {
            if (f32) {
                ws[OFF_W1F + idx] = ((const float*)W1)[idx];
                ws[OFF_W2F + idx] = ((const float*)W2)[idx];
            } else {
                ws[OFF_W1F + idx] = bf2f_raw(((const unsigned short*)W1)[idx]);
                ws[OFF_W2F + idx] = bf2f_raw(((const unsigned short*)W2)[idx]);
            }
        }
        if (idx < 8192)
            ws[OFF_WOUTF + idx] = f32 ? ((const float*)Wout)[idx]
                                      : bf2f_raw(((const unsigned short*)Wout)[idx]);
        if (idx < 128) {
            if (f32) {
                ws[OFF_A1F + idx]   = ((const float*)a1)[idx];
                ws[OFF_A2F + idx]   = ((const float*)a2)[idx];
                ws[OFF_AOUTF + idx] = ((const float*)aout)[idx];
            } else {
                ws[OFF_A1F + idx]   = bf2f_raw(((const unsigned short*)a1)[idx]);
                ws[OFF_A2F + idx]   = bf2f_raw(((const unsigned short*)a2)[idx]);
                ws[OFF_AOUTF + idx] = bf2f_raw(((const unsigned short*)aout)[idx]);
            }
        }
        if (idx < 64) {
            if (f32) {
                ws[OFF_CBF + idx] = ((const float*)conv_b)[idx];
                ws[OFF_TBF + idx] = ((const float*)tconv_b)[idx];
            } else {
                ws[OFF_CBF + idx] = bf2f_raw(((const unsigned short*)conv_b)[idx]);
                ws[OFF_TBF + idx] = bf2f_raw(((const unsigned short*)tconv_b)[idx]);
            }
        }
    } else if (bx < 432) {
        int t = (bx - 144) * 256 + tid;              // < 73728
        int b   = __builtin_amdgcn_readfirstlane(t / 36864);   // 64 | 36864
        int r   = t % 36864;
        int ocb = __builtin_amdgcn_readfirstlane((r / 2304) * 4); // 64 | 2304
        int n   = r % 2304;
        bool f32 = detect_f32(conv_w);
        if (f32) conv_body_raw<true >(x, conv_w, conv_b, ws, n, ocb, b);
        else     conv_body_raw<false>(x, conv_w, conv_b, ws, n, ocb, b);
    }
    gridbar(ws, NBLK * 1);

    // ---- P1: k2 exact top-7 (R1 structure, proven optimum) -----------------
    {
        __shared__ float Bs[32][256];     // 32 KB; doubles as ys[16][264]
        float* ysp = &Bs[0][0];
        int i0 = (bx % 288) * 16;
        int jh = bx / 288;                // 0..2
        int b  = i0 / N_;
        const float* fT  = ws + OFF_BUF0 + (size_t)b * 64 * N_;
        const float* fnc = ws + OFF_BUF2;
        const float* sq  = ws + OFF_SQ + b * N_;
        int w = tid >> 6, lane = tid & 63;
        int r0 = w * 4;
        int arow0 = __builtin_amdgcn_readfirstlane(i0 + r0);

        u64 K[7];
        #pragma unroll
        for (int t = 0; t < 7; ++t) K[t] = ~0ull;
        int rsel = tid >> 4;
        int g    = tid & 15;

        for (int jt = 0; jt < 3; ++jt) {
            int jb = jh * 768 + jt * 256;
            float acc[4][4];
            #pragma unroll
            for (int r = 0; r < 4; ++r)
                #pragma unroll
                for (int c = 0; c < 4; ++c) acc[r][c] = 0.f;

            for (int kh = 0; kh < 2; ++kh) {
                __syncthreads();
                #pragma unroll
                for (int it = 0; it < 8; ++it) {
                    int idx = tid + it * 256;
                    int k = idx >> 6, j4 = idx & 63;
                    float4 v = *(const float4*)(fT + (size_t)(kh * 32 + k) * N_ + jb + j4 * 4);
                    *(float4*)&Bs[k][j4 * 4] = v;
                }
                __syncthreads();

                #pragma unroll 2
                for (int k4 = 0; k4 < 8; ++k4) {
                    float4 Bv[4];
                    #pragma unroll
                    for (int kk = 0; kk < 4; ++kk)
                        Bv[kk] = *(const float4*)&Bs[k4 * 4 + kk][4 * lane];
                    #pragma unroll
                    for (int r = 0; r < 4; ++r) {
                        float4 a = *(const float4*)(fnc + (size_t)(arow0 + r) * 64
                                                    + kh * 32 + k4 * 4);
                        acc[r][0] += a.x * Bv[0].x + a.y * Bv[1].x + a.z * Bv[2].x + a.w * Bv[3].x;
                        acc[r][1] += a.x * Bv[0].y + a.y * Bv[1].y + a.z * Bv[2].y + a.w * Bv[3].y;
                        acc[r][2] += a.x * Bv[0].z + a.y * Bv[1].z + a.z * Bv[2].z + a.w * Bv[3].z;
                        acc[r][3] += a.x * Bv[0].w + a.y * Bv[1].w + a.z * Bv[2].w + a.w * Bv[3].w;
                    }
                }
            }

            __syncthreads();
            float4 sqv = *(const float4*)(sq + jb + 4 * lane);
            #pragma unroll
            for (int r = 0; r < 4; ++r) {
                float4 yv;
                yv.x = sqv.x - 2.f * acc[r][0];
                yv.y = sqv.y - 2.f * acc[r][1];
                yv.z = sqv.z - 2.f * acc[r][2];
                yv.w = sqv.w - 2.f * acc[r][3];
                *(float4*)&ysp[(r0 + r) * 264 + 4 * lane] = yv;
            }
            #pragma unroll 4
            for (int u = 0; u < 16; ++u) {
                int jl = g + 16 * u;
                float y = ysp[rsel * 264 + jl];
                u64 key = ((u64)mono32(y) << 32) | (unsigned int)(jb + jl);
                if (key < K[6]) {
                    int pos = 0;
                    #pragma unroll
                    for (int s = 0; s < 7; ++s) pos += (K[s] < key) ? 1 : 0;
                    #pragma unroll
                    for (int p = 6; p > 0; --p)
                        K[p] = (p == pos) ? key : ((p > pos) ? K[p - 1] : K[p]);
                    if (pos == 0) K[0] = key;
                }
            }
            __syncthreads();
        }

        u64 myk = 0;
        for (int pass = 0; pass < 7; ++pass) {
            u64 m = K[0];
            #pragma unroll
            for (int s = 1; s < 7; ++s) m = (K[s] < m) ? K[s] : m;
            #pragma unroll
            for (int off = 1; off < 16; off <<= 1) {
                u64 o = (u64)__shfl_xor((long long)m, off);
                m = (o < m) ? o : m;
            }
            #pragma unroll
            for (int s = 0; s < 7; ++s)
                if (K[s] == m) K[s] = ~0ull;
            if (g == pass) myk = m;
        }
        if (g < 7) {
            u64* pk = (u64*)(ws + OFF_PK);
            pk[((size_t)(i0 + rsel) * 3 + jh) * 8 + g] = myk;
        }
    }
    gridbar(ws, NBLK * 2);

    // ---- P2: k_lin projections + 3-way KNN rank-merge ----------------------
    if (bx < 594) {
        int g = bx / 18, xb = bx % 18;
        if (g == 32) {
            int row = xb * 256 + tid;   // < 4608
            const u64* pk = (const u64*)(ws + OFF_PK) + (size_t)row * 24;
            int* kout = (int*)(ws + OFF_KNN) + (size_t)row * 8;
            u64 L0[7], L1[7], L2[7];
            #pragma unroll
            for (int q = 0; q < 7; ++q) { L0[q] = pk[q]; L1[q] = pk[8 + q]; L2[q] = pk[16 + q]; }
            #pragma unroll
            for (int q = 0; q < 7; ++q) {
                int rank = q;
                #pragma unroll
                for (int p = 0; p < 7; ++p)
                    rank += ((L1[p] < L0[q]) ? 1 : 0) + ((L2[p] < L0[q]) ? 1 : 0);
                if (rank < 7) kout[rank] = (int)(L0[q] & 0xffffffffull);
            }
            #pragma unroll
            for (int q = 0; q < 7; ++q) {
                int rank = q;
                #pragma unroll
                for (int p = 0; p < 7; ++p)
                    rank += ((L0[p] < L1[q]) ? 1 : 0) + ((L2[p] < L1[q]) ? 1 : 0);
                if (rank < 7) kout[rank] = (int)(L1[q] & 0xffffffffull);
            }
            #pragma unroll
            for (int q = 0; q < 7; ++q) {
                int rank = q;
                #pragma unroll
                for (int p = 0; p < 7; ++p)
                    rank += ((L0[p] < L2[q]) ? 1 : 0) + ((L1[p] < L2[q]) ? 1 : 0);
                if (rank < 7) kout[rank] = (int)(L2[q] & 0xffffffffull);
            }
        } else {
            int layer = g >> 4;
            int ocb = (g & 15) * 4;
            const float* W  = ws + (layer ? OFF_W2F : OFF_W1F);
            const float* a  = ws + (layer ? OFF_A2F : OFF_A1F);
            float* out_nc   = ws + (layer ? OFF_BUF3 : OFF_BUF1);
            float* s1       = ws + (layer ? OFF_S21 : OFF_S11);
            float* s2       = ws + (layer ? OFF_S22 : OFF_S12);
            int i = xb * 256 + tid;
            int b = i / N_, n = i - b * N_;
            const float* in_b = ws + OFF_BUF0 + (size_t)b * 64 * N_;

            float acc[4] = {0, 0, 0, 0};
            #pragma unroll 8
            for (int kk = 0; kk < 64; ++kk) {
                float xv = in_b[kk * N_ + n];
                const float* wr = W + kk * 64 + ocb;
                #pragma unroll
                for (int o = 0; o < 4; ++o) acc[o] += xv * wr[o];
            }
            *(float4*)(out_nc + ((size_t)i * 64 + ocb)) =
                make_float4(acc[0], acc[1], acc[2], acc[3]);
            float p1 = 0.f, p2 = 0.f;
            #pragma unroll
            for (int o = 0; o < 4; ++o) {
                p1 += acc[o] * a[ocb + o];
                p2 += acc[o] * a[64 + ocb + o];
            }
            atomicAdd(s1 + i, p1);
            atomicAdd(s2 + i, p2);
        }
    }
    gridbar(ws, NBLK * 3);

    // ---- P3: attn layers 1+2 ----------------------------------------------
    if (bx < 576) {
        int layer = bx / 288, c = bx % 288;
        int c4 = c / 18, xb = c % 18;
        const float* Wh_nc = ws + (layer ? OFF_BUF3 : OFF_BUF1);
        const float* s1    = ws + (layer ? OFF_S21 : OFF_S11);
        const float* s2    = ws + (layer ? OFF_S22 : OFF_S12);
        float* out         = ws + (layer ? OFF_BUF0 : OFF_BUF2);
        int i = xb * 256 + tid;
        int b = i / N_, n = i - b * N_;
        attn_body(Wh_nc, s1, s2, (const int*)(ws + OFF_KNN), out, i, b, n, c4);
    }
    gridbar(ws, NBLK * 4);

    // ---- P4: lin2 ([h1|h2] @ Wout) ----------------------------------------
    if (bx < 288) {
        int c4g = bx / 18, xb = bx % 18;
        int ocb = c4g * 4;
        int i = xb * 256 + tid;
        int b = i / N_, n = i - b * N_;
        const float* h1 = ws + OFF_BUF2 + (size_t)b * 64 * N_;
        const float* h2 = ws + OFF_BUF0 + (size_t)b * 64 * N_;
        const float* W  = ws + OFF_WOUTF;
        const float* a  = ws + OFF_AOUTF;

        float acc[4] = {0, 0, 0, 0};
        #pragma unroll 8
        for (int kk = 0; kk < 64; ++kk) {
            float xv = h1[kk * N_ + n];
            const float* wr = W + kk * 64 + ocb;
            #pragma unroll
            for (int o = 0; o < 4; ++o) acc[o] += xv * wr[o];
        }
        #pragma unroll 8
        for (int kk = 0; kk < 64; ++kk) {
            float xv = h2[kk * N_ + n];
            const float* wr = W + (64 + kk) * 64 + ocb;
            #pragma unroll
            for (int o = 0; o < 4; ++o) acc[o] += xv * wr[o];
        }
        *(float4*)(ws + OFF_BUF1 + ((size_t)i * 64 + ocb)) =
            make_float4(acc[0], acc[1], acc[2], acc[3]);
        float p1 = 0.f, p2 = 0.f;
        #pragma unroll
        for (int o = 0; o < 4; ++o) {
            p1 += acc[o] * a[ocb + o];
            p2 += acc[o] * a[64 + ocb + o];
        }
        atomicAdd(ws + OFF_S1O + i, p1);
        atomicAdd(ws + OFF_S2O + i, p2);
    }
    gridbar(ws, NBLK * 5);

    // ---- P5: attn out -----------------------------------------------------
    if (bx < 288) {
        int c4 = bx / 18, xb = bx % 18;
        int i = xb * 256 + tid;
        int b = i / N_, n = i - b * N_;
        attn_body(ws + OFF_BUF1, ws + OFF_S1O, ws + OFF_S2O,
                  (const int*)(ws + OFF_KNN), ws + OFF_BUF3, i, b, n, c4);
    }
    gridbar(ws, NBLK * 6);

    // ---- P6: tconv (parity-specialized) -----------------------------------
    if (bx < 576) {
        bool f32 = ws[OFF_FLAG] != 0.f;
        int t = bx * 256 + tid;                       // < 147456
        int tid_old = t & 127;
        int blk = t >> 7;                             // wave-uniform
        int xo = __builtin_amdgcn_readfirstlane(blk % 18);
        int gg = __builtin_amdgcn_readfirstlane((blk / 18) % 32);
        int b  = __builtin_amdgcn_readfirstlane(blk / 576);
        int pixc = xo * 128 + tid_old;                // 0..2303 within class
        int pc   = gg >> 3, ocb = (gg & 7) * 8;
        int py = pc >> 1, px = pc & 1;
        int ay = pixc / 48, bxx = pixc - (pixc / 48) * 48;
        int oy = 2 * ay + py, ox = 2 * bxx + px;

        const float* gT  = ws + OFF_BUF3 + (size_t)b * 64 * N_;
        const float* wt2 = ws + OFF_WT2;
        float acc[8] = {0, 0, 0, 0, 0, 0, 0, 0};

        int nky = py ? 2 : 1;
        int nkx = px ? 2 : 1;
        for (int s = 0; s < nky; ++s) {
            int ky = py ? (s == 0 ? 0 : 2) : 1;
            int iy = py ? (s == 0 ? ay + 1 : ay) : ay;
            bool vy = iy < 48;
            for (int u = 0; u < nkx; ++u) {
                int kx = px ? (u == 0 ? 0 : 2) : 1;
                int ix = px ? (u == 0 ? bxx + 1 : bxx) : bxx;
                bool v = vy && (ix < 48);
                const float* gp = gT + (v ? iy * 48 + ix : 0);
                const float* wb = wt2 + (ky * 3 + kx) * 4096 + ocb;
                #pragma unroll 8
                for (int ic = 0; ic < 64; ++ic) {
                    float gv = gp[ic * N_];
                    gv = v ? gv : 0.f;
                    const float* wr = wb + ic * 64;
                    #pragma unroll
                    for (int o = 0; o < 8; ++o) acc[o] += gv * wr[o];
                }
            }
        }
        const float* tb = ws + OFF_TBF;
        size_t base = ((size_t)(b * 64 + ocb) * 96 + oy) * 96 + ox;
        if (f32) {
            float* op = (float*)outp;
            #pragma unroll
            for (int o = 0; o < 8; ++o) op[base + (size_t)o * 9216] = acc[o] + tb[ocb + o];
        } else {
            bf16* op = (bf16*)outp;
            #pragma unroll
            for (int o = 0; o < 8; ++o)
                op[base + (size_t)o * 9216] = __float2bfloat16(acc[o] + tb[ocb + o]);
        }
    }
}

// ---------------------------------------------------------------------------
extern "C" void kernel_launch(void* const* d_in, const int* in_sizes, int n_in,
                              void* d_out, int out_size, void* d_ws, size_t ws_size,
                              hipStream_t stream)
{
    float* ws = (float*)d_ws;
    // zero FLAG + barrier counter + SQ + six s-arrays (contiguous span)
    hipMemsetAsync(ws + OFF_FLAG, 0, (size_t)(OFF_KNN - OFF_FLAG) * 4, stream);
    hipLaunchKernelGGL(k_all, dim3(NBLK), dim3(256), 0, stream,
                       d_in[0], d_in[1], d_in[2], d_in[3], d_in[4], d_in[5],
                       d_in[6], d_in[7], d_in[8], d_in[9], d_in[10],
                       ws, d_out);
}